// Round 12
// baseline (283.654 us; speedup 1.0000x reference)
//
#include <hip/hip_runtime.h>
#include <cstdint>

#define D 128
#define NEG 0.2f

typedef __attribute__((ext_vector_type(8))) short bf16x8;
typedef __attribute__((ext_vector_type(4))) float f32x4;

__device__ __forceinline__ float wsum(float v){
#pragma unroll
  for(int m=32;m;m>>=1) v += __shfl_xor(v,m,64);
  return v;
}
__device__ __forceinline__ float lrelu(float a){ return a>0.f ? a : NEG*a; }
__device__ __forceinline__ unsigned short f2bf(float f){
  unsigned int u = __float_as_uint(f);
  u += 0x7fffu + ((u>>16)&1u);
  return (unsigned short)(u>>16);
}
__device__ __forceinline__ float bf2f(unsigned short s){
  return __uint_as_float(((unsigned int)s)<<16);
}

// ---- deg histogram from dstv only ----
__global__ __launch_bounds__(256) void k_hist(const int* __restrict__ dstv, int* __restrict__ deg, int E){
  int e = blockIdx.x*256 + threadIdx.x;
  if (e < E) atomicAdd(deg + dstv[e], 1);
}

// ---- scan part 1 (per-block sums) + fused init (weae + W transpose/cvt) ----
__global__ __launch_bounds__(256) void k_scan1i(const int* __restrict__ deg, int* __restrict__ bsum, int N, int NB,
                                                const float* __restrict__ We1, const float* __restrict__ ae1,
                                                const float* __restrict__ We2, const float* __restrict__ ae2,
                                                const float* __restrict__ W1,  const float* __restrict__ W2,
                                                float* __restrict__ weae, ushort* __restrict__ Wtb){
  __shared__ int s[256];
  __shared__ ushort lds[16][128];
  int b = blockIdx.x;
  if (b < NB){
    int i = b*256 + threadIdx.x;
    s[threadIdx.x] = (i < N) ? deg[i] : 0;
    __syncthreads();
#pragma unroll
    for (int st = 128; st; st >>= 1){
      if (threadIdx.x < st) s[threadIdx.x] += s[threadIdx.x + st];
      __syncthreads();
    }
    if (!threadIdx.x) bsum[b] = s[0];
  } else if (b < NB + 64){
    int gw  = ((b - NB)*256 + threadIdx.x) >> 6;
    int lane = threadIdx.x & 63;
    const float* We = (gw & 128) ? We2 : We1;
    const float* ae = (gw & 128) ? ae2 : ae1;
    int row = gw & 127;
    float2 v = ((const float2*)(We + (size_t)row*D))[lane];
    float2 a = ((const float2*)ae)[lane];
    float p = wsum(v.x*a.x + v.y*a.y);
    if (!lane) weae[gw] = p;
  } else {
    int bb = b - NB - 64;        // 0..15
    int layer = bb >> 3;
    int kb = (bb & 7) * 16;
    const float* W = layer ? W2 : W1;
    int t = threadIdx.x;
#pragma unroll
    for (int p = 0; p < 8; ++p){
      int idx = t + p*256;
      int kl = idx >> 7, c = idx & 127;
      lds[kl][c] = f2bf(W[(size_t)(kb+kl)*128 + c]);
    }
    __syncthreads();
    int c = t >> 1, kc = (t & 1) * 8;
    ushort tmp[8];
#pragma unroll
    for (int m = 0; m < 8; ++m) tmp[m] = lds[kc+m][c];
    *(uint4*)&Wtb[(size_t)layer*16384 + (size_t)c*128 + kb + kc] = *(uint4*)tmp;
  }
}

// ---- scan parts 2+3 fused ----
__global__ __launch_bounds__(256) void k_scan23(const int* __restrict__ deg, const int* __restrict__ bsum,
                                                int* __restrict__ rowp, int NB, int N, int E){
  __shared__ int s[256];
  int t = threadIdx.x;
  int v = (t < NB) ? bsum[t] : 0;
  s[t] = v; __syncthreads();
  for (int d = 1; d < 256; d <<= 1){
    int x = (t >= d) ? s[t-d] : 0;
    __syncthreads();
    s[t] += x;
    __syncthreads();
  }
  int boff = (blockIdx.x == 0) ? 0 : s[blockIdx.x - 1];
  __syncthreads();
  int i = blockIdx.x*256 + t;
  int dv = (i < N) ? deg[i] : 0;
  s[t] = dv; __syncthreads();
  for (int d = 1; d < 256; d <<= 1){
    int x = (t >= d) ? s[t-d] : 0;
    __syncthreads();
    s[t] += x;
    __syncthreads();
  }
  if (i < N) rowp[i] = boff + s[t] - dv;
  if (i == N-1) rowp[N] = E;
}

// ---- GEMM tile body (device fn; one 64-row tile) ----
__device__ void gemm_tile(int blk, const float* Xf, const ushort* Xb, const ushort* Wtb,
                          const float* atts, const float* attd, ushort* Hb,
                          float* a_s, float* a_d, int N, ushort* xsb, ushort* wsb, int tid){
  int rowbase = blk*64;
  if (Xf){
#pragma unroll
    for (int i = 0; i < 4; ++i){
      int idx = tid + i*256;
      int r = idx >> 4, ch = idx & 15;
      int gr = rowbase + r;
      int grc = (gr < N) ? gr : 0;
      const float4* src = (const float4*)(Xf + (size_t)grc*128 + ch*8);
      float4 a = src[0], b = src[1];
      uint4 o;
      o.x = (unsigned)f2bf(a.x) | ((unsigned)f2bf(a.y)<<16);
      o.y = (unsigned)f2bf(a.z) | ((unsigned)f2bf(a.w)<<16);
      o.z = (unsigned)f2bf(b.x) | ((unsigned)f2bf(b.y)<<16);
      o.w = (unsigned)f2bf(b.z) | ((unsigned)f2bf(b.w)<<16);
      *(uint4*)&xsb[r*136 + ch*8] = o;
    }
  } else {
#pragma unroll
    for (int i = 0; i < 4; ++i){
      int idx = tid + i*256;
      int r = idx >> 4, ch = idx & 15;
      int gr = rowbase + r;
      int grc = (gr < N) ? gr : 0;
      *(uint4*)&xsb[r*136 + ch*8] = *(const uint4*)&Xb[(size_t)grc*128 + ch*8];
    }
  }
#pragma unroll
  for (int i = 0; i < 8; ++i){
    int idx = tid + i*256;
    int c = idx >> 4, ch = idx & 15;
    *(uint4*)&wsb[c*136 + ch*8] = *(const uint4*)&Wtb[(size_t)c*128 + ch*8];
  }
  __syncthreads();

  int lane = tid & 63;
  int w    = tid >> 6;
  int l15  = lane & 15;
  int lg   = lane >> 4;
  int r0   = w*16;

  f32x4 acc[8];
#pragma unroll
  for (int ct = 0; ct < 8; ++ct) acc[ct] = (f32x4){0.f,0.f,0.f,0.f};

#pragma unroll
  for (int ks = 0; ks < 4; ++ks){
    bf16x8 af = *(const bf16x8*)&xsb[(r0 + l15)*136 + ks*32 + lg*8];
#pragma unroll
    for (int ct = 0; ct < 8; ++ct){
      bf16x8 bfr = *(const bf16x8*)&wsb[(ct*16 + l15)*136 + ks*32 + lg*8];
      acc[ct] = __builtin_amdgcn_mfma_f32_16x16x32_bf16(af, bfr, acc[ct], 0, 0, 0);
    }
  }

  float attsv[8], attdv[8];
#pragma unroll
  for (int ct = 0; ct < 8; ++ct){
    attsv[ct] = atts[ct*16 + l15];
    attdv[ct] = attd[ct*16 + l15];
  }
  float ps[4] = {0,0,0,0}, pd[4] = {0,0,0,0};
#pragma unroll
  for (int ct = 0; ct < 8; ++ct)
#pragma unroll
    for (int j = 0; j < 4; ++j){
      ps[j] += acc[ct][j]*attsv[ct];
      pd[j] += acc[ct][j]*attdv[ct];
    }
#pragma unroll
  for (int m = 1; m <= 8; m <<= 1)
#pragma unroll
    for (int j = 0; j < 4; ++j){
      ps[j] += __shfl_xor(ps[j], m, 64);
      pd[j] += __shfl_xor(pd[j], m, 64);
    }
#pragma unroll
  for (int j = 0; j < 4; ++j){
    int gr = rowbase + r0 + lg*4 + j;
    if (gr < N && l15 == 0){
      a_s[gr] = ps[j];
      a_d[gr] = pd[j];
    }
  }
#pragma unroll
  for (int ct = 0; ct < 8; ++ct)
#pragma unroll
    for (int j = 0; j < 4; ++j){
      int r = r0 + lg*4 + j;
      xsb[r*136 + ct*16 + l15] = f2bf(acc[ct][j]);
    }
  __syncthreads();
#pragma unroll
  for (int i = 0; i < 4; ++i){
    int idx = tid + i*256;
    int r = idx >> 4, ch = idx & 15;
    int gr = rowbase + r;
    if (gr < N)
      *(uint4*)&Hb[(size_t)gr*128 + ch*8] = *(const uint4*)&xsb[r*136 + ch*8];
  }
}

// ---- merged: blocks [0,GEMMB) = layer-1 GEMM; blocks [GEMMB, GEMMB+EB) = edge pass (x2 unroll) ----
__global__ __launch_bounds__(256) void k_edge_gemm1(const float* __restrict__ EA,
                                                    const int* __restrict__ srcv, const int* __restrict__ dstv,
                                                    const float* __restrict__ weae,
                                                    const int* __restrict__ rowp, int* __restrict__ cursor,
                                                    uint2* __restrict__ pl1, uint2* __restrict__ pl2, int E,
                                                    const float* __restrict__ x, const ushort* __restrict__ Wtb,
                                                    const float* __restrict__ a1s, const float* __restrict__ a1d,
                                                    ushort* __restrict__ hb,
                                                    float* __restrict__ as_, float* __restrict__ ad_,
                                                    int N, int GEMMB, int EB){
  __shared__ ushort xsb[64*136];
  __shared__ ushort wsb[128*136];
  int tid = threadIdx.x;
  int b   = blockIdx.x;
  if (b < GEMMB){
    gemm_tile(b, x, nullptr, Wtb, a1s, a1d, hb, as_, ad_, N, xsb, wsb, tid);
    return;
  }
  int eb = b - GEMMB;
  int l   = tid & 63;
  int sub = l & 7;
  int grp = l >> 3;
  float4 w1v[4], w2v[4];
#pragma unroll
  for (int k = 0; k < 4; ++k){
    w1v[k] = ((const float4*)weae)[sub + 8*k];
    w2v[k] = ((const float4*)weae)[32 + sub + 8*k];
  }
  int gwave  = (eb*256 + tid) >> 6;
  int nwaves = EB*4;
  for (int e0 = gwave*16; e0 < E; e0 += nwaves*16){
    int eA = e0 + grp;
    int eB2 = e0 + 8 + grp;
    bool okA = eA < E, okB = eB2 < E;
    const float4* rowA = (const float4*)(EA + (size_t)(okA ? eA : 0)*D);
    const float4* rowB = (const float4*)(EA + (size_t)(okB ? eB2 : 0)*D);
    float4 vA[4], vB[4];
#pragma unroll
    for (int k = 0; k < 4; ++k){ vA[k] = rowA[sub + 8*k]; vB[k] = rowB[sub + 8*k]; }
    float s1a = 0.f, s2a = 0.f, s1b = 0.f, s2b = 0.f;
#pragma unroll
    for (int k = 0; k < 4; ++k){
      s1a += vA[k].x*w1v[k].x + vA[k].y*w1v[k].y + vA[k].z*w1v[k].z + vA[k].w*w1v[k].w;
      s2a += vA[k].x*w2v[k].x + vA[k].y*w2v[k].y + vA[k].z*w2v[k].z + vA[k].w*w2v[k].w;
      s1b += vB[k].x*w1v[k].x + vB[k].y*w1v[k].y + vB[k].z*w1v[k].z + vB[k].w*w1v[k].w;
      s2b += vB[k].x*w2v[k].x + vB[k].y*w2v[k].y + vB[k].z*w2v[k].z + vB[k].w*w2v[k].w;
    }
#pragma unroll
    for (int m = 1; m <= 4; m <<= 1){
      s1a += __shfl_xor(s1a, m, 64);
      s2a += __shfl_xor(s2a, m, 64);
      s1b += __shfl_xor(s1b, m, 64);
      s2b += __shfl_xor(s2b, m, 64);
    }
    if (!sub && okA){
      int d = dstv[eA];
      int pos = rowp[d] + atomicAdd(cursor + d, 1);
      unsigned s = (unsigned)srcv[eA];
      pl1[pos] = make_uint2(s, __float_as_uint(s1a));
      pl2[pos] = make_uint2(s, __float_as_uint(s2a));
    }
    if (!sub && okB){
      int d = dstv[eB2];
      int pos = rowp[d] + atomicAdd(cursor + d, 1);
      unsigned s = (unsigned)srcv[eB2];
      pl1[pos] = make_uint2(s, __float_as_uint(s1b));
      pl2[pos] = make_uint2(s, __float_as_uint(s2b));
    }
  }
}

// ---- standalone GEMM (layer 2) ----
__global__ __launch_bounds__(256) void k_gemm(const ushort* __restrict__ Xb, const ushort* __restrict__ Wtb,
                                              const float* __restrict__ atts, const float* __restrict__ attd,
                                              ushort* __restrict__ Hb,
                                              float* __restrict__ a_s, float* __restrict__ a_d, int N){
  __shared__ ushort xsb[64*136];
  __shared__ ushort wsb[128*136];
  gemm_tile(blockIdx.x, nullptr, Xb, Wtb, atts, attd, Hb, a_s, a_d, N, xsb, wsb, threadIdx.x);
}

// ---- aggregation: fully fused; granularity-4 tail (less padded-gather waste) ----
__global__ __launch_bounds__(256) void k_aggr(const ushort* __restrict__ Hb,
                                              const float* __restrict__ a_s, const float* __restrict__ a_d,
                                              const int* __restrict__ rowp, const uint2* __restrict__ pl,
                                              const float* __restrict__ bias,
                                              float* __restrict__ OUTF, ushort* __restrict__ OUTB, int N){
  __shared__ uint2 lse[4][64];
  int wslot = threadIdx.x >> 6;
  int wid  = (blockIdx.x*blockDim.x + threadIdx.x) >> 6;
  int lane = threadIdx.x & 63;
  if (wid >= N) return;
  int p0 = rowp[wid], p1 = rowp[wid+1];
  float as_own = a_s[wid];
  float ad     = a_d[wid];
  int l32 = lane & 31;
  int hw  = lane >> 5;
  ushort4 uself = make_ushort4(0,0,0,0);
  if (!hw) uself = *(const ushort4*)(Hb + (size_t)wid*D + l32*4);
  float denom = 0.f, sumae = 0.f;
  float4 acc = {0.f,0.f,0.f,0.f};
  for (int c0 = p0; c0 < p1; c0 += 64){
    int p = c0 + lane;
    bool valid = p < p1;
    uint2 rec = valid ? pl[p] : make_uint2(0u, 0u);
    float ae = valid ? __uint_as_float(rec.y) : 0.f;
    float ex = valid ? __expf(lrelu(a_s[rec.x] + ad + ae)) : 0.f;
    sumae += wsum(ae);
    denom += wsum(ex);
    lse[wslot][lane] = make_uint2(rec.x, __float_as_uint(ex));
    int cnt = p1 - c0; if (cnt > 64) cnt = 64;   // wave-uniform
    int nfull = cnt & ~15;
    for (int it = 0; it*16 < nfull; ++it){
      int base = it*16 + hw*8;
#pragma unroll
      for (int k = 0; k < 8; ++k){
        uint2 t = lse[wslot][base + k];
        float w2 = __uint_as_float(t.y);
        ushort4 u = *(const ushort4*)(Hb + (size_t)t.x*D + l32*4);
        acc.x += w2*bf2f(u.x); acc.y += w2*bf2f(u.y);
        acc.z += w2*bf2f(u.z); acc.w += w2*bf2f(u.w);
      }
    }
    for (int j0 = nfull; j0 < cnt; j0 += 4){
      int base = j0 + hw*2;
#pragma unroll
      for (int k = 0; k < 2; ++k){
        uint2 t = lse[wslot][base + k];     // slots >= cnt are ex=0 pads
        float w2 = __uint_as_float(t.y);
        ushort4 u = *(const ushort4*)(Hb + (size_t)t.x*D + l32*4);
        acc.x += w2*bf2f(u.x); acc.y += w2*bf2f(u.y);
        acc.z += w2*bf2f(u.z); acc.w += w2*bf2f(u.w);
      }
    }
  }
  float dg = (float)(p1 - p0);
  float la = sumae / fmaxf(dg, 1.0f);
  float ex_self = __expf(lrelu(as_own + ad + la));
  denom += ex_self;
  acc.x += __shfl_xor(acc.x, 32);
  acc.y += __shfl_xor(acc.y, 32);
  acc.z += __shfl_xor(acc.z, 32);
  acc.w += __shfl_xor(acc.w, 32);
  if (!hw){
    acc.x += ex_self*bf2f(uself.x); acc.y += ex_self*bf2f(uself.y);
    acc.z += ex_self*bf2f(uself.z); acc.w += ex_self*bf2f(uself.w);
    float4 bv = *(const float4*)(bias + l32*4);
    float inv = 1.0f/denom;
    float ox = acc.x*inv + bv.x, oy = acc.y*inv + bv.y;
    float oz = acc.z*inv + bv.z, ow = acc.w*inv + bv.w;
    if (OUTB){
      ox=fmaxf(ox,0.f); oy=fmaxf(oy,0.f); oz=fmaxf(oz,0.f); ow=fmaxf(ow,0.f);
      ushort4 o;
      o.x=f2bf(ox); o.y=f2bf(oy); o.z=f2bf(oz); o.w=f2bf(ow);
      *(ushort4*)(OUTB + (size_t)wid*D + l32*4) = o;
    } else {
      *(float4*)(OUTF + (size_t)wid*D + l32*4) = make_float4(ox,oy,oz,ow);
    }
  }
}

extern "C" void kernel_launch(void* const* d_in, const int* in_sizes, int n_in,
                              void* d_out, int out_size, void* d_ws, size_t ws_size,
                              hipStream_t stream){
  (void)n_in; (void)out_size; (void)ws_size;
  const float* x   = (const float*)d_in[0];
  const int*   ei  = (const int*)d_in[1];
  const float* ea  = (const float*)d_in[2];
  const float* W1  = (const float*)d_in[3];
  const float* a1s = (const float*)d_in[4];
  const float* a1d = (const float*)d_in[5];
  const float* We1 = (const float*)d_in[6];
  const float* ae1 = (const float*)d_in[7];
  const float* b1  = (const float*)d_in[8];
  const float* W2  = (const float*)d_in[9];
  const float* a2s = (const float*)d_in[10];
  const float* a2d = (const float*)d_in[11];
  const float* We2 = (const float*)d_in[12];
  const float* ae2 = (const float*)d_in[13];
  const float* b2  = (const float*)d_in[14];
  int N = in_sizes[0] / D;
  int E = in_sizes[1] / 2;
  const int* srcv = ei;
  const int* dstv = ei + E;
  float* out = (float*)d_out;

  char* p = (char*)d_ws;
  auto allocB = [&](size_t bytes)->void*{
    void* r = (void*)p; p += (bytes + 255) & ~(size_t)255; return r;
  };
  int* deg     = (int*)allocB((size_t)N*4);
  int* cursor  = (int*)allocB((size_t)N*4);
  char* zero_end = p;
  ushort* hb   = (ushort*)allocB((size_t)N*D*2);
  ushort* x2b  = (ushort*)allocB((size_t)N*D*2);
  ushort* Wtb  = (ushort*)allocB((size_t)2*128*128*2);
  uint2* pl1   = (uint2*)allocB((size_t)E*8);
  uint2* pl2   = (uint2*)allocB((size_t)E*8);
  float* as_   = (float*)allocB((size_t)N*4);
  float* ad_   = (float*)allocB((size_t)N*4);
  float* weae  = (float*)allocB(1024);
  int* rowp    = (int*)allocB((size_t)(N+1)*4);
  int* bsum    = (int*)allocB(1024);

  hipMemsetAsync(deg, 0, (size_t)(zero_end - (char*)deg), stream);

  int nb = (N + 255)/256;
  int gemmb = (N + 63)/64;
  int edgeb = 2048;
  int wgrid = (N + 3)/4;

  k_hist   <<<(E+255)/256,256,0,stream>>>(dstv, deg, E);
  k_scan1i <<<nb+80,256,0,stream>>>(deg, bsum, N, nb, We1,ae1,We2,ae2,W1,W2, weae, Wtb);
  k_scan23 <<<nb,256,0,stream>>>(deg, bsum, rowp, nb, N, E);
  // edge pass + layer-1 GEMM in one dispatch (independent work)
  k_edge_gemm1<<<gemmb+edgeb,256,0,stream>>>(ea, srcv, dstv, weae, rowp, cursor, pl1, pl2, E,
                                             x, Wtb, a1s, a1d, hb, as_, ad_, N, gemmb, edgeb);
  k_aggr<<<wgrid,256,0,stream>>>(hb, as_, ad_, rowp, pl1, b1, nullptr, x2b, N);
  k_gemm<<<gemmb,256,0,stream>>>(x2b, Wtb + 16384, a2s, a2d, hb, as_, ad_, N);
  k_aggr<<<wgrid,256,0,stream>>>(hb, as_, ad_, rowp, pl2, b2, out, nullptr, N);
}

// Round 13
// 266.298 us; speedup vs baseline: 1.0652x; 1.0652x over previous
//
#include <hip/hip_runtime.h>
#include <cstdint>

#define D 128
#define NEG 0.2f

typedef __attribute__((ext_vector_type(8))) short bf16x8;
typedef __attribute__((ext_vector_type(4))) float f32x4;

__device__ __forceinline__ float wsum(float v){
#pragma unroll
  for(int m=32;m;m>>=1) v += __shfl_xor(v,m,64);
  return v;
}
__device__ __forceinline__ float lrelu(float a){ return a>0.f ? a : NEG*a; }
__device__ __forceinline__ unsigned short f2bf(float f){
  unsigned int u = __float_as_uint(f);
  u += 0x7fffu + ((u>>16)&1u);
  return (unsigned short)(u>>16);
}
__device__ __forceinline__ float bf2f(unsigned short s){
  return __uint_as_float(((unsigned int)s)<<16);
}

// ---- deg histogram ----
__global__ __launch_bounds__(256) void k_hist(const int* __restrict__ dstv, int* __restrict__ deg, int E){
  int e = blockIdx.x*256 + threadIdx.x;
  if (e < E) atomicAdd(deg + dstv[e], 1);
}

// ---- scan part 1 + fused init (weae + W transpose/cvt) ----
__global__ __launch_bounds__(256) void k_scan1i(const int* __restrict__ deg, int* __restrict__ bsum, int N, int NB,
                                                const float* __restrict__ We1, const float* __restrict__ ae1,
                                                const float* __restrict__ We2, const float* __restrict__ ae2,
                                                const float* __restrict__ W1,  const float* __restrict__ W2,
                                                float* __restrict__ weae, ushort* __restrict__ Wtb){
  __shared__ int s[256];
  __shared__ ushort lds[16][128];
  int b = blockIdx.x;
  if (b < NB){
    int i = b*256 + threadIdx.x;
    s[threadIdx.x] = (i < N) ? deg[i] : 0;
    __syncthreads();
#pragma unroll
    for (int st = 128; st; st >>= 1){
      if (threadIdx.x < st) s[threadIdx.x] += s[threadIdx.x + st];
      __syncthreads();
    }
    if (!threadIdx.x) bsum[b] = s[0];
  } else if (b < NB + 64){
    int gw  = ((b - NB)*256 + threadIdx.x) >> 6;
    int lane = threadIdx.x & 63;
    const float* We = (gw & 128) ? We2 : We1;
    const float* ae = (gw & 128) ? ae2 : ae1;
    int row = gw & 127;
    float2 v = ((const float2*)(We + (size_t)row*D))[lane];
    float2 a = ((const float2*)ae)[lane];
    float p = wsum(v.x*a.x + v.y*a.y);
    if (!lane) weae[gw] = p;
  } else {
    int bb = b - NB - 64;
    int layer = bb >> 3;
    int kb = (bb & 7) * 16;
    const float* W = layer ? W2 : W1;
    int t = threadIdx.x;
#pragma unroll
    for (int p = 0; p < 8; ++p){
      int idx = t + p*256;
      int kl = idx >> 7, c = idx & 127;
      lds[kl][c] = f2bf(W[(size_t)(kb+kl)*128 + c]);
    }
    __syncthreads();
    int c = t >> 1, kc = (t & 1) * 8;
    ushort tmp[8];
#pragma unroll
    for (int m = 0; m < 8; ++m) tmp[m] = lds[kc+m][c];
    *(uint4*)&Wtb[(size_t)layer*16384 + (size_t)c*128 + kb + kc] = *(uint4*)tmp;
  }
}

// ---- scan parts 2+3 fused ----
__global__ __launch_bounds__(256) void k_scan23(const int* __restrict__ deg, const int* __restrict__ bsum,
                                                int* __restrict__ rowp, int NB, int N, int E){
  __shared__ int s[256];
  int t = threadIdx.x;
  int v = (t < NB) ? bsum[t] : 0;
  s[t] = v; __syncthreads();
  for (int d = 1; d < 256; d <<= 1){
    int x = (t >= d) ? s[t-d] : 0;
    __syncthreads();
    s[t] += x;
    __syncthreads();
  }
  int boff = (blockIdx.x == 0) ? 0 : s[blockIdx.x - 1];
  __syncthreads();
  int i = blockIdx.x*256 + t;
  int dv = (i < N) ? deg[i] : 0;
  s[t] = dv; __syncthreads();
  for (int d = 1; d < 256; d <<= 1){
    int x = (t >= d) ? s[t-d] : 0;
    __syncthreads();
    s[t] += x;
    __syncthreads();
  }
  if (i < N) rowp[i] = boff + s[t] - dv;
  if (i == N-1) rowp[N] = E;
}

// ---- edge pass: 8 lanes/edge, no LDS (max occupancy); ONE scattered 16B record per edge ----
__global__ __launch_bounds__(256) void k_edge(const float* __restrict__ EA,
                                              const int* __restrict__ srcv, const int* __restrict__ dstv,
                                              const float* __restrict__ weae,
                                              const int* __restrict__ rowp, int* __restrict__ cursor,
                                              int4* __restrict__ csr, int E){
  int l   = threadIdx.x & 63;
  int sub = l & 7;
  int grp = l >> 3;
  float4 w1v[4], w2v[4];
#pragma unroll
  for (int k = 0; k < 4; ++k){
    w1v[k] = ((const float4*)weae)[sub + 8*k];
    w2v[k] = ((const float4*)weae)[32 + sub + 8*k];
  }
  int gwave  = (blockIdx.x*blockDim.x + threadIdx.x) >> 6;
  int nwaves = (gridDim.x*blockDim.x) >> 6;
  for (int e0 = gwave*8; e0 < E; e0 += nwaves*8){
    int e = e0 + grp;
    if (e >= E) continue;
    const float4* row = (const float4*)(EA + (size_t)e*D);
    float s1 = 0.f, s2 = 0.f;
#pragma unroll
    for (int k = 0; k < 4; ++k){
      float4 v = row[sub + 8*k];
      s1 += v.x*w1v[k].x + v.y*w1v[k].y + v.z*w1v[k].z + v.w*w1v[k].w;
      s2 += v.x*w2v[k].x + v.y*w2v[k].y + v.z*w2v[k].z + v.w*w2v[k].w;
    }
#pragma unroll
    for (int m = 1; m <= 4; m <<= 1){
      s1 += __shfl_xor(s1, m, 64);
      s2 += __shfl_xor(s2, m, 64);
    }
    if (!sub){
      int d = dstv[e];
      int pos = rowp[d] + atomicAdd(cursor + d, 1);
      csr[pos] = make_int4(srcv[e], __float_as_int(s1), __float_as_int(s2), 0);
    }
  }
}

// ---- MFMA GEMM: Hb = bf16(X @ W) + fused a_s/a_d epilogue; coalesced store via LDS repack ----
__global__ __launch_bounds__(256) void k_gemm(const float* __restrict__ Xf, const ushort* __restrict__ Xb,
                                              const ushort* __restrict__ Wtb,
                                              const float* __restrict__ atts, const float* __restrict__ attd,
                                              ushort* __restrict__ Hb,
                                              float* __restrict__ a_s, float* __restrict__ a_d, int N){
  __shared__ ushort xsb[64*136];
  __shared__ ushort wsb[128*136];
  int tid = threadIdx.x;
  int rowbase = blockIdx.x*64;
  if (Xf){
#pragma unroll
    for (int i = 0; i < 4; ++i){
      int idx = tid + i*256;
      int r = idx >> 4, ch = idx & 15;
      int gr = rowbase + r;
      int grc = (gr < N) ? gr : 0;
      const float4* src = (const float4*)(Xf + (size_t)grc*128 + ch*8);
      float4 a = src[0], b = src[1];
      uint4 o;
      o.x = (unsigned)f2bf(a.x) | ((unsigned)f2bf(a.y)<<16);
      o.y = (unsigned)f2bf(a.z) | ((unsigned)f2bf(a.w)<<16);
      o.z = (unsigned)f2bf(b.x) | ((unsigned)f2bf(b.y)<<16);
      o.w = (unsigned)f2bf(b.z) | ((unsigned)f2bf(b.w)<<16);
      *(uint4*)&xsb[r*136 + ch*8] = o;
    }
  } else {
#pragma unroll
    for (int i = 0; i < 4; ++i){
      int idx = tid + i*256;
      int r = idx >> 4, ch = idx & 15;
      int gr = rowbase + r;
      int grc = (gr < N) ? gr : 0;
      *(uint4*)&xsb[r*136 + ch*8] = *(const uint4*)&Xb[(size_t)grc*128 + ch*8];
    }
  }
#pragma unroll
  for (int i = 0; i < 8; ++i){
    int idx = tid + i*256;
    int c = idx >> 4, ch = idx & 15;
    *(uint4*)&wsb[c*136 + ch*8] = *(const uint4*)&Wtb[(size_t)c*128 + ch*8];
  }
  __syncthreads();

  int lane = tid & 63;
  int w    = tid >> 6;
  int l15  = lane & 15;
  int lg   = lane >> 4;
  int r0   = w*16;

  f32x4 acc[8];
#pragma unroll
  for (int ct = 0; ct < 8; ++ct) acc[ct] = (f32x4){0.f,0.f,0.f,0.f};

#pragma unroll
  for (int ks = 0; ks < 4; ++ks){
    bf16x8 af = *(const bf16x8*)&xsb[(r0 + l15)*136 + ks*32 + lg*8];
#pragma unroll
    for (int ct = 0; ct < 8; ++ct){
      bf16x8 bfr = *(const bf16x8*)&wsb[(ct*16 + l15)*136 + ks*32 + lg*8];
      acc[ct] = __builtin_amdgcn_mfma_f32_16x16x32_bf16(af, bfr, acc[ct], 0, 0, 0);
    }
  }

  float attsv[8], attdv[8];
#pragma unroll
  for (int ct = 0; ct < 8; ++ct){
    attsv[ct] = atts[ct*16 + l15];
    attdv[ct] = attd[ct*16 + l15];
  }
  float ps[4] = {0,0,0,0}, pd[4] = {0,0,0,0};
#pragma unroll
  for (int ct = 0; ct < 8; ++ct)
#pragma unroll
    for (int j = 0; j < 4; ++j){
      ps[j] += acc[ct][j]*attsv[ct];
      pd[j] += acc[ct][j]*attdv[ct];
    }
#pragma unroll
  for (int m = 1; m <= 8; m <<= 1)
#pragma unroll
    for (int j = 0; j < 4; ++j){
      ps[j] += __shfl_xor(ps[j], m, 64);
      pd[j] += __shfl_xor(pd[j], m, 64);
    }
#pragma unroll
  for (int j = 0; j < 4; ++j){
    int gr = rowbase + r0 + lg*4 + j;
    if (gr < N && l15 == 0){
      a_s[gr] = ps[j];
      a_d[gr] = pd[j];
    }
  }
#pragma unroll
  for (int ct = 0; ct < 8; ++ct)
#pragma unroll
    for (int j = 0; j < 4; ++j){
      int r = r0 + lg*4 + j;
      xsb[r*136 + ct*16 + l15] = f2bf(acc[ct][j]);
    }
  __syncthreads();
#pragma unroll
  for (int i = 0; i < 4; ++i){
    int idx = tid + i*256;
    int r = idx >> 4, ch = idx & 15;
    int gr = rowbase + r;
    if (gr < N)
      *(uint4*)&Hb[(size_t)gr*128 + ch*8] = *(const uint4*)&xsb[r*136 + ch*8];
  }
}

// ---- aggregation: fused exp/sum/self-loop/softmax/gather; 16B csr records; granularity-4 tail ----
__global__ __launch_bounds__(256) void k_aggr(const ushort* __restrict__ Hb,
                                              const float* __restrict__ a_s, const float* __restrict__ a_d,
                                              const int* __restrict__ rowp, const int4* __restrict__ csr,
                                              int layer,
                                              const float* __restrict__ bias,
                                              float* __restrict__ OUTF, ushort* __restrict__ OUTB, int N){
  __shared__ uint2 lse[4][64];
  int wslot = threadIdx.x >> 6;
  int wid  = (blockIdx.x*blockDim.x + threadIdx.x) >> 6;
  int lane = threadIdx.x & 63;
  if (wid >= N) return;
  int p0 = rowp[wid], p1 = rowp[wid+1];
  float as_own = a_s[wid];
  float ad     = a_d[wid];
  int l32 = lane & 31;
  int hw  = lane >> 5;
  ushort4 uself = make_ushort4(0,0,0,0);
  if (!hw) uself = *(const ushort4*)(Hb + (size_t)wid*D + l32*4);
  float denom = 0.f, sumae = 0.f;
  float4 acc = {0.f,0.f,0.f,0.f};
  for (int c0 = p0; c0 < p1; c0 += 64){
    int p = c0 + lane;
    bool valid = p < p1;
    int4 rec = valid ? csr[p] : make_int4(0,0,0,0);
    float ae = valid ? __int_as_float(layer ? rec.z : rec.y) : 0.f;
    float ex = valid ? __expf(lrelu(a_s[rec.x] + ad + ae)) : 0.f;
    sumae += wsum(ae);
    denom += wsum(ex);
    lse[wslot][lane] = make_uint2((unsigned)rec.x, __float_as_uint(ex));
    int cnt = p1 - c0; if (cnt > 64) cnt = 64;   // wave-uniform
    int nfull = cnt & ~15;
    for (int it = 0; it*16 < nfull; ++it){
      int base = it*16 + hw*8;
#pragma unroll
      for (int k = 0; k < 8; ++k){
        uint2 t = lse[wslot][base + k];
        float w2 = __uint_as_float(t.y);
        ushort4 u = *(const ushort4*)(Hb + (size_t)t.x*D + l32*4);
        acc.x += w2*bf2f(u.x); acc.y += w2*bf2f(u.y);
        acc.z += w2*bf2f(u.z); acc.w += w2*bf2f(u.w);
      }
    }
    for (int j0 = nfull; j0 < cnt; j0 += 4){
      int base = j0 + hw*2;
#pragma unroll
      for (int k = 0; k < 2; ++k){
        uint2 t = lse[wslot][base + k];     // slots >= cnt are ex=0 pads
        float w2 = __uint_as_float(t.y);
        ushort4 u = *(const ushort4*)(Hb + (size_t)t.x*D + l32*4);
        acc.x += w2*bf2f(u.x); acc.y += w2*bf2f(u.y);
        acc.z += w2*bf2f(u.z); acc.w += w2*bf2f(u.w);
      }
    }
  }
  float dg = (float)(p1 - p0);
  float la = sumae / fmaxf(dg, 1.0f);
  float ex_self = __expf(lrelu(as_own + ad + la));
  denom += ex_self;
  acc.x += __shfl_xor(acc.x, 32);
  acc.y += __shfl_xor(acc.y, 32);
  acc.z += __shfl_xor(acc.z, 32);
  acc.w += __shfl_xor(acc.w, 32);
  if (!hw){
    acc.x += ex_self*bf2f(uself.x); acc.y += ex_self*bf2f(uself.y);
    acc.z += ex_self*bf2f(uself.z); acc.w += ex_self*bf2f(uself.w);
    float4 bv = *(const float4*)(bias + l32*4);
    float inv = 1.0f/denom;
    float ox = acc.x*inv + bv.x, oy = acc.y*inv + bv.y;
    float oz = acc.z*inv + bv.z, ow = acc.w*inv + bv.w;
    if (OUTB){
      ox=fmaxf(ox,0.f); oy=fmaxf(oy,0.f); oz=fmaxf(oz,0.f); ow=fmaxf(ow,0.f);
      ushort4 o;
      o.x=f2bf(ox); o.y=f2bf(oy); o.z=f2bf(oz); o.w=f2bf(ow);
      *(ushort4*)(OUTB + (size_t)wid*D + l32*4) = o;
    } else {
      *(float4*)(OUTF + (size_t)wid*D + l32*4) = make_float4(ox,oy,oz,ow);
    }
  }
}

extern "C" void kernel_launch(void* const* d_in, const int* in_sizes, int n_in,
                              void* d_out, int out_size, void* d_ws, size_t ws_size,
                              hipStream_t stream){
  (void)n_in; (void)out_size; (void)ws_size;
  const float* x   = (const float*)d_in[0];
  const int*   ei  = (const int*)d_in[1];
  const float* ea  = (const float*)d_in[2];
  const float* W1  = (const float*)d_in[3];
  const float* a1s = (const float*)d_in[4];
  const float* a1d = (const float*)d_in[5];
  const float* We1 = (const float*)d_in[6];
  const float* ae1 = (const float*)d_in[7];
  const float* b1  = (const float*)d_in[8];
  const float* W2  = (const float*)d_in[9];
  const float* a2s = (const float*)d_in[10];
  const float* a2d = (const float*)d_in[11];
  const float* We2 = (const float*)d_in[12];
  const float* ae2 = (const float*)d_in[13];
  const float* b2  = (const float*)d_in[14];
  int N = in_sizes[0] / D;
  int E = in_sizes[1] / 2;
  const int* srcv = ei;
  const int* dstv = ei + E;
  float* out = (float*)d_out;

  char* p = (char*)d_ws;
  auto allocB = [&](size_t bytes)->void*{
    void* r = (void*)p; p += (bytes + 255) & ~(size_t)255; return r;
  };
  int* deg     = (int*)allocB((size_t)N*4);
  int* cursor  = (int*)allocB((size_t)N*4);
  char* zero_end = p;
  ushort* hb   = (ushort*)allocB((size_t)N*D*2);
  ushort* x2b  = (ushort*)allocB((size_t)N*D*2);
  ushort* Wtb  = (ushort*)allocB((size_t)2*128*128*2);
  int4* csr    = (int4*)allocB((size_t)E*16);
  float* as_   = (float*)allocB((size_t)N*4);
  float* ad_   = (float*)allocB((size_t)N*4);
  float* weae  = (float*)allocB(1024);
  int* rowp    = (int*)allocB((size_t)(N+1)*4);
  int* bsum    = (int*)allocB(1024);

  hipMemsetAsync(deg, 0, (size_t)(zero_end - (char*)deg), stream);

  int nb = (N + 255)/256;
  int gemmb = (N + 63)/64;
  int wgrid = (N + 3)/4;

  k_hist   <<<(E+255)/256,256,0,stream>>>(dstv, deg, E);
  k_scan1i <<<nb+80,256,0,stream>>>(deg, bsum, N, nb, We1,ae1,We2,ae2,W1,W2, weae, Wtb);
  k_scan23 <<<nb,256,0,stream>>>(deg, bsum, rowp, nb, N, E);
  k_edge   <<<2048,256,0,stream>>>(ea, srcv, dstv, weae, rowp, cursor, csr, E);

  // layer 1
  k_gemm<<<gemmb,256,0,stream>>>(x, nullptr, Wtb,          a1s, a1d, hb, as_, ad_, N);
  k_aggr<<<wgrid,256,0,stream>>>(hb, as_, ad_, rowp, csr, 0, b1, nullptr, x2b, N);

  // layer 2
  k_gemm<<<gemmb,256,0,stream>>>(nullptr, x2b, Wtb + 16384, a2s, a2d, hb, as_, ad_, N);
  k_aggr<<<wgrid,256,0,stream>>>(hb, as_, ad_, rowp, csr, 1, b2, out, nullptr, N);
}